// Round 9
// baseline (1066.056 us; speedup 1.0000x reference)
//
#include <hip/hip_runtime.h>
#include <hip/hip_bf16.h>
#include <math.h>

// B=8, S=1024, D=768, H=12, DH=64, L=3, I=3072, W1S=128, nc=8, MLP=512, NCLS=3

typedef __attribute__((ext_vector_type(8))) short short8;   // 8 bf16 (4 VGPRs)
typedef __attribute__((ext_vector_type(4))) short short4v;  // 4 bf16 (8 B)
typedef __attribute__((ext_vector_type(4))) float floatx4;  // MFMA C/D

// Exact-accuracy gelu via A&S 7.1.26 rational erf (|err|<=1.5e-7).
__device__ __forceinline__ float gelu_exact(float x) {
    float ax = fabsf(x) * 0.70710678118654752440f;
    float t  = 1.f / (1.f + 0.3275911f * ax);
    float y  = t * (0.254829592f + t * (-0.284496736f + t * (1.421413741f +
               t * (-1.453152027f + t * 1.061405429f))));
    float erfv = copysignf(1.f - y * __expf(-ax * ax), x);
    return 0.5f * x * (1.f + erfv);
}

__device__ __forceinline__ short bfs(float x) {
    __hip_bfloat16 h = __float2bfloat16(x);
    short s;
    __builtin_memcpy(&s, &h, 2);
    return s;
}

__device__ __forceinline__ float bf2f(short s) {
    unsigned u = ((unsigned)(unsigned short)s) << 16;
    float f;
    __builtin_memcpy(&f, &u, 4);
    return f;
}

#define GLOAD_LDS16(g, l) __builtin_amdgcn_global_load_lds( \
    (const __attribute__((address_space(1))) void*)(g),     \
    (__attribute__((address_space(3))) void*)(l), 16, 0, 0)

// ---------------------------------------------------------------------------
// R14/R16: ALL weight prep + patchify gather in ONE launch.
// (R14 won 1087.3 -> 1066.6 by fusing 10 prep launches; R16 folds gather_x's
// 1.57M elements = exactly 6144 x 256 in as job 3.) Compile-time job table;
// branches block-uniform.
// Grid: 21840 transpose tiles + 27 bias-pack + 6144 gather = 28011.
// ---------------------------------------------------------------------------
__global__ __launch_bounds__(256) void weight_prep(
    const float* __restrict__ wq, const float* __restrict__ wk,
    const float* __restrict__ wv, const float* __restrict__ wo,
    const float* __restrict__ wi, const float* __restrict__ wo2,
    const float* __restrict__ pj, const float* __restrict__ pw,
    const float* __restrict__ h1,
    const float* __restrict__ bq, const float* __restrict__ bk,
    const float* __restrict__ bv,
    const float* __restrict__ x,
    __hip_bfloat16* __restrict__ qkvw_t, __hip_bfloat16* __restrict__ wo_t,
    __hip_bfloat16* __restrict__ wi_t, __hip_bfloat16* __restrict__ wo2_t,
    __hip_bfloat16* __restrict__ projw_t, __hip_bfloat16* __restrict__ poolw_t,
    __hip_bfloat16* __restrict__ w1_t, float* __restrict__ qkv_b,
    __hip_bfloat16* __restrict__ xr)
{
    int gid = blockIdx.x;
    if (gid >= 21867) {                       // patchify gather (6144 blocks)
        int idx = (gid - 21867) * 256 + threadIdx.x;   // 0..1572863 exact
        int tok = idx / 192, f = idx - tok * 192;
        int b = tok >> 10, s = tok & 1023;
        int tci = s >> 6, sci = (s >> 3) & 7, scj = s & 7;
        int ch  = f % 3;
        int crc = f / 3;
        int cr1 = crc >> 4, cr2 = (crc >> 2) & 3, cr3 = crc & 3;
        float v = x[(((b * 3 + ch) * 64) + cr1 * 16 + tci) * 1024 +
                    (cr2 * 8 + sci) * 32 + cr3 * 8 + scj];
        xr[(long)tok * 192 + f] = __float2bfloat16(v);
        return;
    }
    if (gid >= 21840) {                       // qkv bias pack (27 blocks)
        int idx = (gid - 21840) * 256 + threadIdx.x;
        if (idx < 6912) {
            int l = idx / 2304, r = idx - l * 2304;
            float v = (r < 768) ? bq[l * 768 + r]
                    : (r < 1536) ? bk[l * 768 + r - 768]
                                 : bv[l * 768 + r - 1536];
            qkv_b[idx] = v;
        }
        return;
    }
    const float* W; __hip_bfloat16* Wt;
    int K, N, tx, tpl, local;
    long inLS, outLS;
    if (gid < 6912) {                         // wq,wk,wv,wo: 24x24x3 each
        int j = gid / 1728; local = gid - j * 1728;
        K = 768; N = 768; tx = 24; tpl = 576; inLS = 589824;
        if      (j == 0) { W = wq; Wt = qkvw_t;           outLS = 1769472; }
        else if (j == 1) { W = wk; Wt = qkvw_t + 589824;  outLS = 1769472; }
        else if (j == 2) { W = wv; Wt = qkvw_t + 1179648; outLS = 1769472; }
        else             { W = wo; Wt = wo_t;             outLS = 589824;  }
    } else if (gid < 13824) {                 // wi: 96x24x3
        local = gid - 6912;  W = wi;  Wt = wi_t;
        K = 768; N = 3072; tx = 96; tpl = 2304; inLS = 2359296; outLS = 2359296;
    } else if (gid < 20736) {                 // wo2: 24x96x3
        local = gid - 13824; W = wo2; Wt = wo2_t;
        K = 3072; N = 768; tx = 24; tpl = 2304; inLS = 2359296; outLS = 2359296;
    } else if (gid < 20880) {                 // proj: 24x6
        local = gid - 20736; W = pj;  Wt = projw_t;
        K = 192; N = 768; tx = 24; tpl = 144; inLS = 0; outLS = 0;
    } else if (gid < 21456) {                 // pool: 24x24
        local = gid - 20880; W = pw;  Wt = poolw_t;
        K = 768; N = 768; tx = 24; tpl = 576; inLS = 0; outLS = 0;
    } else {                                  // hw1: 16x24
        local = gid - 21456; W = h1;  Wt = w1_t;
        K = 768; N = 512; tx = 16; tpl = 384; inLS = 0; outLS = 0;
    }
    int l   = local / tpl;
    int rem = local - l * tpl;
    int bx = rem % tx, by = rem / tx;
    __shared__ float tile[32][33];
    const float* Wl = W + (long)l * inLS;
    __hip_bfloat16* Wtl = Wt + (long)l * outLS;
    int lx = threadIdx.x & 31, ly = threadIdx.x >> 5;
    int kb = by * 32, nb = bx * 32;
    #pragma unroll
    for (int r = 0; r < 32; r += 8)
        tile[ly + r][lx] = Wl[(long)(kb + ly + r) * N + nb + lx];
    __syncthreads();
    #pragma unroll
    for (int r = 0; r < 32; r += 8)
        Wtl[(long)(nb + ly + r) * K + kb + lx] = __float2bfloat16(tile[lx][ly + r]);
}

// ---------------------------------------------------------------------------
// bf16 MFMA GEMM: C[M,N](bf16) = A[M,K](bf16) @ Bt[N,K](bf16)^T + bias.
// 128x128 tile, BK=64 (R15: won 1066.6 -> 1048.3; halves barrier drains per
// K-sweep). 64KB LDS, 2 blocks/CU. Streamed bf fragments. Structure is at
// the m97-family plateau after R1-R8 parameter sweep.
// ---------------------------------------------------------------------------
template<int ACT>
__global__ __launch_bounds__(256, 4) void mfma_gemm(
    const __hip_bfloat16* __restrict__ A, const __hip_bfloat16* __restrict__ Bt,
    const float* __restrict__ bias, __hip_bfloat16* __restrict__ C,
    int M, int N, int K)
{
    __shared__ short lds_raw[32768];   // 64KB: A[2][2][128][32] | B at +16384
    short* LB = lds_raw;
    int tid  = threadIdx.x;
    int wave = tid >> 6, lane = tid & 63;
    int L = blockIdx.x;
    long m0 = (long)(L & 63) * 128, n0 = (long)(L >> 6) * 128;
    int wr = wave >> 1, wc = wave & 1;
    floatx4 acc[4][4] = {};

    int srow = (wave * 128 + lane) >> 2;            // wave*32 + lane/4
    int sch  = (lane & 3) ^ ((lane >> 3) & 3);      // source-side XOR swizzle
    const __hip_bfloat16* Ag = A  + (m0 + srow) * K + sch * 8;
    const __hip_bfloat16* Bg = Bt + (n0 + srow) * K + sch * 8;
    int lm = lane & 15, lg = lane >> 4;
    int lk8 = ((lg ^ ((lm >> 1) & 3))) * 8;         // read-side swizzle

    auto stage = [&](int buf, int k0) {
        short* a0 = LB + buf * 8192 + wave * 1024;          // chunk k0
        short* a1 = a0 + 4096;                              // chunk k0+32
        short* b0 = LB + 16384 + buf * 8192 + wave * 1024;
        short* b1 = b0 + 4096;
        GLOAD_LDS16(Ag + k0,               a0);
        GLOAD_LDS16(Ag + 16 * K + k0,      a0 + 512);
        GLOAD_LDS16(Ag + k0 + 32,          a1);
        GLOAD_LDS16(Ag + 16 * K + k0 + 32, a1 + 512);
        GLOAD_LDS16(Bg + k0,               b0);
        GLOAD_LDS16(Bg + 16 * K + k0,      b0 + 512);
        GLOAD_LDS16(Bg + k0 + 32,          b1);
        GLOAD_LDS16(Bg + 16 * K + k0 + 32, b1 + 512);
    };

    stage(0, 0);
    int buf = 0;
    for (int k0 = 0; k0 < K; k0 += 64, buf ^= 1) {
        __syncthreads();                 // buf's 8 loads landed; prev reads done
        if (k0 + 64 < K) stage(buf ^ 1, k0 + 64);
        #pragma unroll
        for (int c = 0; c < 2; c++) {
            const __hip_bfloat16* Ab =
                (const __hip_bfloat16*)(LB + buf * 8192 + c * 4096);
            const __hip_bfloat16* Bb =
                (const __hip_bfloat16*)(LB + 16384 + buf * 8192 + c * 4096);
            short8 af[4];
            #pragma unroll
            for (int mi = 0; mi < 4; mi++)
                af[mi] = *(const short8*)&Ab[(wr * 64 + mi * 16 + lm) * 32 + lk8];
            #pragma unroll
            for (int ni = 0; ni < 4; ni++) {
                short8 bf = *(const short8*)&Bb[(wc * 64 + ni * 16 + lm) * 32 + lk8];
                #pragma unroll
                for (int mi = 0; mi < 4; mi++)
                    acc[mi][ni] = __builtin_amdgcn_mfma_f32_16x16x32_bf16(
                        af[mi], bf, acc[mi][ni], 0, 0, 0);
            }
        }
    }
    __syncthreads();

    // ---- epilogue: bias(+gelu), LDS transpose, coalesced bf16 stores ----
    float bvv[4];
    #pragma unroll
    for (int ni = 0; ni < 4; ni++)
        bvv[ni] = bias[n0 + wc * 64 + ni * 16 + lm];
    int erow = tid >> 4;            // 0..15
    int ecol = (tid & 15) * 8;      // 0..120
    #pragma unroll
    for (int p = 0; p < 2; p++) {
        if (wr == p) {
            #pragma unroll
            for (int mi = 0; mi < 4; mi++)
                #pragma unroll
                for (int ni = 0; ni < 4; ni++)
                    #pragma unroll
                    for (int j = 0; j < 4; j++) {
                        float o = acc[mi][ni][j] + bvv[ni];
                        if (ACT == 1) o = gelu_exact(o);
                        lds_raw[(mi * 16 + lg * 4 + j) * 136 +
                                wc * 64 + ni * 16 + lm] = bfs(o);
                    }
        }
        __syncthreads();
        #pragma unroll
        for (int rr = 0; rr < 4; rr++) {
            int r = erow + rr * 16;
            short8 v = *(const short8*)&lds_raw[r * 136 + ecol];
            *(short8*)&C[(m0 + p * 64 + r) * N + n0 + ecol] = v;
        }
        __syncthreads();
    }
}

// ---------------------------------------------------------------------------
// h = LayerNorm(t_bf + pos_emb[s] + tok_emb); fp32 h + bf16 mirror.
// ---------------------------------------------------------------------------
__global__ __launch_bounds__(192) void pos_ln_kernel(
    const __hip_bfloat16* __restrict__ t, const float* __restrict__ pos_emb,
    const float* __restrict__ tok_emb, const float* __restrict__ ln_s,
    const float* __restrict__ ln_b, float* __restrict__ h,
    __hip_bfloat16* __restrict__ hbf)
{
    int tok = blockIdx.x;
    int s = tok & 1023;
    int tid = threadIdx.x;        // 0..191
    int d = tid * 4;
    __shared__ float red[6];
    short4v tv = *(const short4v*)&t[(long)tok * 768 + d];
    float4 pv = *(const float4*)&pos_emb[s * 768 + d];
    float4 kv = *(const float4*)&tok_emb[d];
    float a[4] = { bf2f(tv[0]) + pv.x + kv.x, bf2f(tv[1]) + pv.y + kv.y,
                   bf2f(tv[2]) + pv.z + kv.z, bf2f(tv[3]) + pv.w + kv.w };
    float sum = a[0] + a[1] + a[2] + a[3];
    float sumsq = a[0]*a[0] + a[1]*a[1] + a[2]*a[2] + a[3]*a[3];
    #pragma unroll
    for (int off = 32; off; off >>= 1) {
        sum   += __shfl_down(sum, off, 64);
        sumsq += __shfl_down(sumsq, off, 64);
    }
    if ((tid & 63) == 0) { red[tid >> 6] = sum; red[3 + (tid >> 6)] = sumsq; }
    __syncthreads();
    sum   = red[0] + red[1] + red[2];
    sumsq = red[3] + red[4] + red[5];
    float mean = sum * (1.f / 768.f);
    float var  = sumsq * (1.f / 768.f) - mean * mean;
    float rs   = rsqrtf(var + 1e-12f);
    float4 sv = *(const float4*)&ln_s[d];
    float4 bv = *(const float4*)&ln_b[d];
    float4 o;
    o.x = (a[0] - mean) * rs * sv.x + bv.x;
    o.y = (a[1] - mean) * rs * sv.y + bv.y;
    o.z = (a[2] - mean) * rs * sv.z + bv.z;
    o.w = (a[3] - mean) * rs * sv.w + bv.w;
    *(float4*)&h[(long)tok * 768 + d] = o;
    short4v ob = { bfs(o.x), bfs(o.y), bfs(o.z), bfs(o.w) };
    *(short4v*)&hbf[(long)tok * 768 + d] = ob;
}

// ---------------------------------------------------------------------------
// MFMA band attention; QKV is bf16 [8192, 2304] (q|k|v packed per token).
// R16: band-mask work skipping (bit-identical output):
//  - whole-tile skip: (tt==0,ci==0) and (tt==2,ci==7) are fully OOB; the
//    online-softmax algebra makes them exact no-ops (al=1/ts=0 path).
//  - per-wave frag skip on edge tiles: frag (w,mt) fully masked iff
//    mt < 2w (tt==0) / mt >= 2w+2 (tt==2) -> skip QK MFMA + mask + exp.
//  - matching PV key-slot skip: kk < w (tt==0) / kk > w (tt==2).
//    frag-skip => slot-skip (verified), so skipped P entries never read;
//    skipped exp terms are exactly 0 (expf(-1e9-m)==0 in f32).
// All predicates wave-uniform (w, tt, ci) -> no divergence.
// ---------------------------------------------------------------------------
__global__ __launch_bounds__(256) void attn_kernel(
    const __hip_bfloat16* __restrict__ QKV, __hip_bfloat16* __restrict__ Ob)
{
    __shared__ __hip_bfloat16 KV[128 * 72];       // Ks[128][72]  /  Vt[64][136]
    __shared__ __hip_bfloat16 Pl[4][32 * 136];    // per-wave P[query][key]
    __shared__ float alpha_s[4][32];
    __shared__ float l_s[4][32];

    int blk = blockIdx.x;
    int ci = blk & 7, hh = (blk >> 3) % 12, b = blk / 96;
    int tid = threadIdx.x, w = tid >> 6, lane = tid & 63;
    int lm = lane & 15, lg = lane >> 4;
    __hip_bfloat16* Pw = &Pl[w][0];

    short8 qf[2][2];
    #pragma unroll
    for (int nt = 0; nt < 2; nt++) {
        int q = ci * 128 + w * 32 + nt * 16 + lm;
        const __hip_bfloat16* qp = &QKV[((long)(b * 1024 + q)) * 2304 + hh * 64];
        #pragma unroll
        for (int ks = 0; ks < 2; ks++)
            qf[nt][ks] = *(const short8*)(qp + ks * 32 + lg * 8);
    }

    floatx4 accO[2][4] = {};
    float m_run[2] = {-1e30f, -1e30f};
    float l_run[2] = {0.f, 0.f};

    for (int tt = 0; tt < 3; tt++) {
        if ((tt == 0 && ci == 0) || (tt == 2 && ci == 7)) continue;  // fully OOB
        __syncthreads();
        #pragma unroll
        for (int i = 0; i < 4; i++) {
            int e = tid + i * 256;          // 0..1023
            int jj = e >> 3, dd = (e & 7) * 8;
            int kpos = ci * 128 + tt * 128 + jj - 128;
            short8 kv = {};
            if (kpos >= 0 && kpos < 1024)
                kv = *(const short8*)&QKV[((long)(b * 1024 + kpos)) * 2304 + 768 + hh * 64 + dd];
            *(short8*)&KV[jj * 72 + dd] = kv;
        }
        __syncthreads();

        floatx4 accS[8][2] = {};
        #pragma unroll
        for (int ks = 0; ks < 2; ks++)
            #pragma unroll
            for (int mt = 0; mt < 8; mt++) {
                if ((tt == 0 && mt < 2 * w) || (tt == 2 && mt >= 2 * w + 2))
                    continue;               // frag fully masked
                short8 kf = *(const short8*)&KV[(mt * 16 + lm) * 72 + ks * 32 + lg * 8];
                accS[mt][0] = __builtin_amdgcn_mfma_f32_16x16x32_bf16(kf, qf[0][ks], accS[mt][0], 0, 0, 0);
                accS[mt][1] = __builtin_amdgcn_mfma_f32_16x16x32_bf16(kf, qf[1][ks], accS[mt][1], 0, 0, 0);
            }

        float tmax[2] = {-1e30f, -1e30f};
        #pragma unroll
        for (int nt = 0; nt < 2; nt++) {
            int r = w * 32 + nt * 16 + lm;
            #pragma unroll
            for (int mt = 0; mt < 8; mt++) {
                if ((tt == 0 && mt < 2 * w) || (tt == 2 && mt >= 2 * w + 2))
                    continue;
                #pragma unroll
                for (int j = 0; j < 4; j++) {
                    int jrel = tt * 128 + mt * 16 + lg * 4 + j;
                    int kpos = ci * 128 + jrel - 128;
                    bool valid = (jrel >= r) && (jrel <= r + 256) &&
                                 (kpos >= 0) && (kpos < 1024);
                    float s = valid ? accS[mt][nt][j] * 0.125f : -1e9f;
                    accS[mt][nt][j] = s;
                    tmax[nt] = fmaxf(tmax[nt], s);
                }
            }
            tmax[nt] = fmaxf(tmax[nt], __shfl_xor(tmax[nt], 16));
            tmax[nt] = fmaxf(tmax[nt], __shfl_xor(tmax[nt], 32));
        }

        float al[2];
        #pragma unroll
        for (int nt = 0; nt < 2; nt++) {
            float mnew = fmaxf(m_run[nt], tmax[nt]);
            al[nt] = __expf(m_run[nt] - mnew);
            m_run[nt] = mnew;
            float ts = 0.f;
            #pragma unroll
            for (int mt = 0; mt < 8; mt++) {
                if ((tt == 0 && mt < 2 * w) || (tt == 2 && mt >= 2 * w + 2))
                    continue;               // exp terms would be exactly 0
                short4v pp;
                #pragma unroll
                for (int j = 0; j < 4; j++) {
                    float p = __expf(accS[mt][nt][j] - mnew);
                    ts += p;
                    pp[j] = bfs(p);
                }
                *(short4v*)&Pw[(nt * 16 + lm) * 136 + mt * 16 + lg * 4] = pp;
            }
            ts += __shfl_xor(ts, 16);
            ts += __shfl_xor(ts, 32);
            l_run[nt] = l_run[nt] * al[nt] + ts;
        }
        if (lg < 2) alpha_s[w][lg * 16 + lm] = al[lg];

        __syncthreads();
        #pragma unroll
        for (int i = 0; i < 4; i++) {
            int e = tid + i * 256;          // 0..1023
            int jj = e >> 3, dd = (e & 7) * 8;
            int kpos = ci * 128 + tt * 128 + jj - 128;
            short8 vv = {};
            if (kpos >= 0 && kpos < 1024)
                vv = *(const short8*)&QKV[((long)(b * 1024 + kpos)) * 2304 + 1536 + hh * 64 + dd];
            short* kvs = (short*)KV;
            #pragma unroll
            for (int m2 = 0; m2 < 8; m2++)
                kvs[(dd + m2) * 136 + jj] = vv[m2];
        }
        __syncthreads();

        #pragma unroll
        for (int mo = 0; mo < 2; mo++)
            #pragma unroll
            for (int j = 0; j < 4; j++) {
                float a = alpha_s[w][mo * 16 + lg * 4 + j];
                #pragma unroll
                for (int nd = 0; nd < 4; nd++)
                    accO[mo][nd][j] *= a;
            }

        #pragma unroll
        for (int kk = 0; kk < 4; kk++) {
            if ((tt == 0 && kk < w) || (tt == 2 && kk > w))
                continue;                   // key slot fully masked (P==0)
            short8 pf[2], vf[4];
            #pragma unroll
            for (int mo = 0; mo < 2; mo++)
                pf[mo] = *(const short8*)&Pw[(mo * 16 + lm) * 136 + kk * 32 + lg * 8];
            #pragma unroll
            for (int nd = 0; nd < 4; nd++)
                vf[nd] = *(const short8*)&KV[(nd * 16 + lm) * 136 + kk * 32 + lg * 8];
            #pragma unroll
            for (int mo = 0; mo < 2; mo++)
                #pragma unroll
                for (int nd = 0; nd < 4; nd++)
                    accO[mo][nd] = __builtin_amdgcn_mfma_f32_16x16x32_bf16(
                        pf[mo], vf[nd], accO[mo][nd], 0, 0, 0);
        }
    }

    if (lg < 2) l_s[w][lg * 16 + lm] = l_run[lg];
    #pragma unroll
    for (int mo = 0; mo < 2; mo++)
        #pragma unroll
        for (int j = 0; j < 4; j++) {
            int qr = mo * 16 + lg * 4 + j;       // within-wave row, 0..31
            float rl = 1.f / l_s[w][qr];
            int q  = w * 32 + qr;
            long base = ((long)(b * 1024 + ci * 128 + q)) * 768 + hh * 64;
            #pragma unroll
            for (int nd = 0; nd < 4; nd++)
                Ob[base + nd * 16 + lm] = __float2bfloat16(accO[mo][nd][j] * rl);
        }
}

// ---------------------------------------------------------------------------
// h = LayerNorm(h + t_bf) in place; bf16 mirror. 192 thr, 16-B vector access.
// ---------------------------------------------------------------------------
__global__ __launch_bounds__(192) void add_ln_kernel(
    float* __restrict__ h, const __hip_bfloat16* __restrict__ t,
    const float* __restrict__ ln_s, const float* __restrict__ ln_b,
    __hip_bfloat16* __restrict__ hbf)
{
    int tok = blockIdx.x;
    int tid = threadIdx.x;        // 0..191
    int d = tid * 4;
    __shared__ float red[6];
    float* hrow = &h[(long)tok * 768];
    float4 hv = *(const float4*)&hrow[d];
    short4v tv = *(const short4v*)&t[(long)tok * 768 + d];
    float a[4] = { hv.x + bf2f(tv[0]), hv.y + bf2f(tv[1]),
                   hv.z + bf2f(tv[2]), hv.w + bf2f(tv[3]) };
    float sum = a[0] + a[1] + a[2] + a[3];
    float sumsq = a[0]*a[0] + a[1]*a[1] + a[2]*a[2] + a[3]*a[3];
    #pragma unroll
    for (int off = 32; off; off >>= 1) {
        sum   += __shfl_down(sum, off, 64);
        sumsq += __shfl_down(sumsq, off, 64);
    }
    if ((tid & 63) == 0) { red[tid >> 6] = sum; red[3 + (tid >> 6)] = sumsq; }
    __syncthreads();
    sum   = red[0] + red[1] + red[2];
    sumsq = red[3] + red[4] + red[5];
    float mean = sum * (1.f / 768.f);
    float var  = sumsq * (1.f / 768.f) - mean * mean;
    float rs   = rsqrtf(var + 1e-12f);
    float4 sv = *(const float4*)&ln_s[d];
    float4 bv = *(const float4*)&ln_b[d];
    float4 o;
    o.x = (a[0] - mean) * rs * sv.x + bv.x;
    o.y = (a[1] - mean) * rs * sv.y + bv.y;
    o.z = (a[2] - mean) * rs * sv.z + bv.z;
    o.w = (a[3] - mean) * rs * sv.w + bv.w;
    *(float4*)&hrow[d] = o;
    short4v ob = { bfs(o.x), bfs(o.y), bfs(o.z), bfs(o.w) };
    *(short4v*)&hbf[(long)tok * 768 + d] = ob;
}

// ---------------------------------------------------------------------------
// R16: entire head (pool -> LN -> MLP -> final) in ONE kernel, 8 blocks
// (one per batch). All stages are block-local once pooled[768] is in LDS.
// Replaces 4 serial launches (~10-14us incl gaps) with one ~5us kernel.
// ---------------------------------------------------------------------------
__global__ __launch_bounds__(256) void head_fused(
    const __hip_bfloat16* __restrict__ hbf,
    const __hip_bfloat16* __restrict__ pool_wt, const float* __restrict__ pool_b,
    const float* __restrict__ hln_s, const float* __restrict__ hln_b,
    const __hip_bfloat16* __restrict__ w1t, const float* __restrict__ b1,
    const float* __restrict__ w2, const float* __restrict__ b2,
    float* __restrict__ out)
{
    __shared__ __hip_bfloat16 hrow[768];
    __shared__ float pooled[768];
    __shared__ float red[8];
    __shared__ __hip_bfloat16 zrow[768];
    __shared__ float z1s[512];
    int b = blockIdx.x, tid = threadIdx.x;
    const __hip_bfloat16* hr = hbf + (long)b * 1024 * 768;   // token 0 of batch b
    #pragma unroll
    for (int r = 0; r < 3; r++) hrow[tid + r * 256] = hr[tid + r * 256];
    __syncthreads();
    // pool: 3 outputs/thread, dot over LDS hrow (broadcast reads)
    #pragma unroll
    for (int rep = 0; rep < 3; rep++) {
        int d = tid + rep * 256;
        const __hip_bfloat16* wr = pool_wt + (long)d * 768;
        float acc = 0.f;
        for (int k = 0; k < 768; k += 8) {
            short8 hv = *(const short8*)&hrow[k];
            short8 wv = *(const short8*)&wr[k];
            #pragma unroll
            for (int j = 0; j < 8; j++) acc += bf2f(hv[j]) * bf2f(wv[j]);
        }
        pooled[d] = tanhf(acc + pool_b[d]);
    }
    __syncthreads();
    // LayerNorm over 768 (block-wide)
    float p0 = pooled[tid], p1 = pooled[tid + 256], p2 = pooled[tid + 512];
    float sum = p0 + p1 + p2;
    float sumsq = p0 * p0 + p1 * p1 + p2 * p2;
    #pragma unroll
    for (int off = 32; off; off >>= 1) {
        sum   += __shfl_down(sum, off, 64);
        sumsq += __shfl_down(sumsq, off, 64);
    }
    if ((tid & 63) == 0) { red[tid >> 6] = sum; red[4 + (tid >> 6)] = sumsq; }
    __syncthreads();
    sum   = red[0] + red[1] + red[2] + red[3];
    sumsq = red[4] + red[5] + red[6] + red[7];
    float mean = sum * (1.f / 768.f);
    float var  = sumsq * (1.f / 768.f) - mean * mean;
    float rs   = rsqrtf(var + 1e-12f);
    zrow[tid]       = __float2bfloat16((p0 - mean) * rs * hln_s[tid]       + hln_b[tid]);
    zrow[tid + 256] = __float2bfloat16((p1 - mean) * rs * hln_s[tid + 256] + hln_b[tid + 256]);
    zrow[tid + 512] = __float2bfloat16((p2 - mean) * rs * hln_s[tid + 512] + hln_b[tid + 512]);
    __syncthreads();
    // MLP: 2 outputs/thread
    #pragma unroll
    for (int rep = 0; rep < 2; rep++) {
        int d = tid + rep * 256;
        const __hip_bfloat16* wr = w1t + (long)d * 768;
        float acc = 0.f;
        for (int k = 0; k < 768; k += 8) {
            short8 zv = *(const short8*)&zrow[k];
            short8 wv = *(const short8*)&wr[k];
            #pragma unroll
            for (int j = 0; j < 8; j++) acc += bf2f(zv[j]) * bf2f(wv[j]);
        }
        z1s[d] = gelu_exact(acc + b1[d]);
    }
    __syncthreads();
    // final 3-class projection
    if (tid < 3) {
        float acc = 0.f;
        for (int k = 0; k < 512; k++) acc += z1s[k] * w2[k * 3 + tid];
        out[b * 3 + tid] = acc + b2[tid];
    }
}

// ---------------------------------------------------------------------------
extern "C" void kernel_launch(void* const* d_in, const int* in_sizes, int n_in,
                              void* d_out, int out_size, void* d_ws, size_t ws_size,
                              hipStream_t stream) {
    const float* x       = (const float*)d_in[0];
    const float* proj_w  = (const float*)d_in[2];
    const float* proj_b  = (const float*)d_in[3];
    const float* pos_emb = (const float*)d_in[4];
    const float* tok_emb = (const float*)d_in[5];
    const float* eln_s   = (const float*)d_in[6];
    const float* eln_b   = (const float*)d_in[7];
    const float* wq      = (const float*)d_in[8];
    const float* bq      = (const float*)d_in[9];
    const float* wk      = (const float*)d_in[10];
    const float* bk      = (const float*)d_in[11];
    const float* wv      = (const float*)d_in[12];
    const float* bv      = (const float*)d_in[13];
    const float* wo      = (const float*)d_in[14];
    const float* bo      = (const float*)d_in[15];
    const float* ln1_s   = (const float*)d_in[16];
    const float* ln1_b   = (const float*)d_in[17];
    const float* wi      = (const float*)d_in[18];
    const float* bi      = (const float*)d_in[19];
    const float* wo2     = (const float*)d_in[20];
    const float* bo2     = (const float*)d_in[21];
    const float* ln2_s   = (const float*)d_in[22];
    const float* ln2_b   = (const float*)d_in[23];
    const float* pool_w  = (const float*)d_in[24];
    const float* pool_b  = (const float*)d_in[25];
    const float* hln_s   = (const float*)d_in[26];
    const float* hln_b   = (const float*)d_in[27];
    const float* hw1     = (const float*)d_in[28];
    const float* hb1     = (const float*)d_in[29];
    const float* hw2     = (const float*)d_in[30];
    const float* hb2     = (const float*)d_in[31];

    char* wp = (char*)d_ws;
    auto alloc = [&](size_t bytes) {
        char* p = wp; wp += (bytes + 255) & ~(size_t)255; return p;
    };
    float*          h       = (float*)alloc(8192ll * 768 * 4);
    __hip_bfloat16* qkv_bf  = (__hip_bfloat16*)alloc(8192ll * 2304 * 2);
    __hip_bfloat16* t_bf    = (__hip_bfloat16*)alloc(8192ll * 768 * 2);
    __hip_bfloat16* mlp_bf  = (__hip_bfloat16*)alloc(8192ll * 3072 * 2);
    __hip_bfloat16* h_bf    = (__hip_bfloat16*)alloc(8192ll * 768 * 2);
    __hip_bfloat16* a_bf    = (__hip_bfloat16*)alloc(8192ll * 768 * 2);
    __hip_bfloat16* qkvw_t  = (__hip_bfloat16*)alloc(3ll * 2304 * 768 * 2);
    __hip_bfloat16* wo_t    = (__hip_bfloat16*)alloc(3ll * 768 * 768 * 2);
    __hip_bfloat16* wi_t    = (__hip_bfloat16*)alloc(3ll * 3072 * 768 * 2);
    __hip_bfloat16* wo2_t   = (__hip_bfloat16*)alloc(3ll * 768 * 3072 * 2);
    float*          qkv_b   = (float*)alloc(3ll * 2304 * 4);
    __hip_bfloat16* xr_bf   = (__hip_bfloat16*)alloc(8192ll * 192 * 2);
    __hip_bfloat16* projw_t = (__hip_bfloat16*)alloc(768ll * 192 * 2);
    __hip_bfloat16* poolw_t = (__hip_bfloat16*)alloc(768ll * 768 * 2);
    __hip_bfloat16* w1_t    = (__hip_bfloat16*)alloc(512ll * 768 * 2);

    // ---- ALL weight conversion + patchify gather in one launch ----
    weight_prep<<<28011, 256, 0, stream>>>(
        wq, wk, wv, wo, wi, wo2, proj_w, pool_w, hw1, bq, bk, bv, x,
        qkvw_t, wo_t, wi_t, wo2_t, projw_t, poolw_t, w1_t, qkv_b, xr_bf);

    // ---- embed as MFMA GEMM ----
    mfma_gemm<0><<<6 * 64, 256, 0, stream>>>(
        xr_bf, projw_t, proj_b, t_bf, 8192, 768, 192);
    pos_ln_kernel<<<8192, 192, 0, stream>>>(t_bf, pos_emb, tok_emb, eln_s, eln_b, h, h_bf);

    for (int l = 0; l < 3; l++) {
        mfma_gemm<0><<<18 * 64, 256, 0, stream>>>(
            h_bf, qkvw_t + (long)l * 2304 * 768, qkv_b + l * 2304, qkv_bf,
            8192, 2304, 768);
        attn_kernel<<<768, 256, 0, stream>>>(qkv_bf, a_bf);
        mfma_gemm<0><<<6 * 64, 256, 0, stream>>>(
            a_bf, wo_t + (long)l * 768 * 768, bo + l * 768, t_bf,
            8192, 768, 768);
        add_ln_kernel<<<8192, 192, 0, stream>>>(h, t_bf, ln1_s + l * 768, ln1_b + l * 768, h_bf);
        mfma_gemm<1><<<24 * 64, 256, 0, stream>>>(
            h_bf, wi_t + (long)l * 3072 * 768, bi + l * 3072, mlp_bf,
            8192, 3072, 768);
        mfma_gemm<0><<<6 * 64, 256, 0, stream>>>(
            mlp_bf, wo2_t + (long)l * 768 * 3072, bo2 + l * 768, t_bf,
            8192, 768, 3072);
        add_ln_kernel<<<8192, 192, 0, stream>>>(h, t_bf, ln2_s + l * 768, ln2_b + l * 768, h_bf);
    }

    // ---- head: pool -> LN -> MLP -> final, fused ----
    head_fused<<<8, 256, 0, stream>>>(h_bf, poolw_t, pool_b, hln_s, hln_b,
                                      w1_t, hb1, hw2, hb2, (float*)d_out);
}